// Round 12
// baseline (106.174 us; speedup 1.0000x reference)
//
#include <hip/hip_runtime.h>

// B=8, N=256, D=128, 2D=256.
// out = tour [8,256] (arange) ++ improvement_matrix [8,256,256].

typedef __attribute__((ext_vector_type(8))) short short8;
typedef __attribute__((ext_vector_type(8))) _Float16 half8;
typedef __attribute__((ext_vector_type(4))) float floatx4;

static __device__ __forceinline__ unsigned short f2bf(float f) {
  unsigned int x = __float_as_uint(f);
  x += 0x7fff + ((x >> 16) & 1);   // RNE fp32 -> bf16
  return (unsigned short)(x >> 16);
}

static __device__ __forceinline__ unsigned short f2h(float f) {
  _Float16 h = (_Float16)f;        // RNE fp32 -> fp16
  return __builtin_bit_cast(unsigned short, h);
}

static __device__ __forceinline__ float fast_tanh(float x) {
  float e = __expf(2.0f * fabsf(x));                       // e^{2|x|}
  float t = 1.0f - 2.0f * __builtin_amdgcn_rcpf(e + 1.0f); // in [0,1)
  return copysignf(t, x);
}

// pack 8 fp16 -> 8 OCP e4m3 bytes (via f32, v_cvt_pk_fp8_f32)
static __device__ __forceinline__ long pack_fp8(half8 s) {
  int lo = __builtin_amdgcn_cvt_pk_fp8_f32((float)s[0], (float)s[1], 0, false);
  lo = __builtin_amdgcn_cvt_pk_fp8_f32((float)s[2], (float)s[3], lo, true);
  int hi = __builtin_amdgcn_cvt_pk_fp8_f32((float)s[4], (float)s[5], 0, false);
  hi = __builtin_amdgcn_cvt_pk_fp8_f32((float)s[6], (float)s[7], hi, true);
  return (long)(unsigned)lo | ((long)hi << 32);
}

// ---- k_prep: tour | zero matrix | W2->fp8(x16) T | W1->bf16 T | xcat bf16 --
__global__ __launch_bounds__(256) void k_prep(
    const float* __restrict__ x, const float* __restrict__ W1,
    const float* __restrict__ W2, float* __restrict__ out,
    unsigned char* __restrict__ W2F8, unsigned short* __restrict__ W1T,
    unsigned short* __restrict__ xcat) {
  int e = blockIdx.x * 256 + threadIdx.x;   // grid covers 1198080
  if (e < 2048) {
    out[e] = (float)(e & 255);              // improved_tour rows = arange
  } else if (e < 526336) {
    out[e] = 0.f;                           // zero matrix (uncovered tiles)
  } else if (e < 542720) {
    int t = e - 526336;                     // 16384 k-pairs of W2
    int p = t >> 7, n = t & 127;            // p = k/2, n = out channel
    float f0 = W2[(2 * p) * 128 + n] * 16.f;       // x16: into e4m3 normal range
    float f1 = W2[(2 * p + 1) * 128 + n] * 16.f;
    int v = __builtin_amdgcn_cvt_pk_fp8_f32(f0, f1, 0, false);
    *(unsigned short*)(W2F8 + n * 256 + 2 * p) = (unsigned short)(v & 0xffff);
  } else if (e < 673792) {
    int e3 = e - 542720;                    // 131072: W1T [512 n][256 k]
    int n = e3 >> 8, k = e3 & 255;
    W1T[e3] = f2bf(W1[((k + (n & 256)) << 8) + (n & 255)]);
  } else {
    int e4 = e - 673792;                    // 524288: xcat [2048 r][256 k]
    int r = e4 >> 8, k = e4 & 255;
    int pos = r & 255;
    int pos2 = (k < 128) ? pos : ((pos + 1) & 255);
    xcat[e4] = f2bf(x[(((r >> 8) << 8) + pos2) * 128 + (k & 127)]);
  }
}

// ---- k_proj: MFMA GEMM  [2048 rows x 256 K] @ [K x 512 ch] -> PiH | PjH ----
__global__ __launch_bounds__(256) void k_proj(
    const unsigned short* __restrict__ xcat, const unsigned short* __restrict__ W1T,
    const float* __restrict__ b1, unsigned short* __restrict__ PiH,
    unsigned short* __restrict__ PjH) {
  const int mg = blockIdx.x >> 3;       // 0..31 row-tile
  const int ng = blockIdx.x & 7;        // 0..7 channel-tile
  const int tid = threadIdx.x;
  const int wr = tid >> 6, lane = tid & 63, quad = lane >> 4, l15 = lane & 15;

  __shared__ unsigned short As[64 * 256];   // 32KB rows tile (swizzled)
  __shared__ unsigned short Bs[64 * 256];   // 32KB W1T tile (swizzled)

#pragma unroll
  for (int it = 0; it < 8; ++it) {
    int e = it * 256 + tid;
    int r = e >> 5, v = e & 31;
    int col = ((v & 16) | ((v ^ (r & 15)) & 15)) << 3;
    *(uint4*)&As[r * 256 + col] = *(const uint4*)(xcat + (mg * 64 + r) * 256 + v * 8);
    *(uint4*)&Bs[r * 256 + col] = *(const uint4*)(W1T + (ng * 64 + r) * 256 + v * 8);
  }
  __syncthreads();

  floatx4 acc[4];
#pragma unroll
  for (int mt = 0; mt < 4; ++mt) acc[mt] = (floatx4)0.f;

  const char* Ab = (const char*)As;
  const char* Bb = (const char*)Bs + wr * 16 * 512;
  const int base_sw = l15 * 512 + ((quad ^ l15) << 4);

#pragma unroll
  for (int ks = 0; ks < 8; ++ks) {
    const int swz = base_sw ^ (ks << 6);
    short8 bfr = *(const short8*)(Bb + swz);
#pragma unroll
    for (int mt = 0; mt < 4; ++mt) {
      short8 afr = *(const short8*)(Ab + mt * 8192 + swz);
      acc[mt] = __builtin_amdgcn_mfma_f32_16x16x32_bf16(afr, bfr, acc[mt], 0, 0, 0);
    }
  }

  const int ch = ng * 64 + wr * 16 + l15;          // 0..511 (wave-uniform side)
  const float bias = (ch < 256) ? b1[ch] : 0.f;
  unsigned short* dst = (ch < 256) ? PiH : PjH;
  const int chan = ch & 255;
#pragma unroll
  for (int mt = 0; mt < 4; ++mt)
#pragma unroll
    for (int r = 0; r < 4; ++r) {
      int row = mg * 64 + mt * 16 + quad * 4 + r;  // global row b*256+pos
      dst[row * 256 + chan] = f2h(acc[mt][r] + bias);
    }
}

// ---- k_main: persistent packed items + fp8 pair-GEMM. ---------------------
// 9088 items total (1136/b x 8b); grid = 512 blocks (2/CU, ALL co-resident,
// no dispatch-round tail); wave-slot w handles items w, w+4096, w+8192.
// W2 e4m3 staged ONCE per block (amortized ~2.2 items/wave); decode via
// magic div (x14769>>24 == /1136 for e<9088) + jt prefix chain.
__global__ __launch_bounds__(512, 4) void k_main(
    const unsigned short* __restrict__ PiH, const unsigned short* __restrict__ PjH,
    const unsigned char* __restrict__ W2F8, const float* __restrict__ b2,
    const float* __restrict__ W3, const float* __restrict__ b3,
    float* __restrict__ outm) {
  const int tid = threadIdx.x;
  const int wr = tid >> 6;              // wave 0..7
  const int lane = tid & 63, quad = lane >> 4, l15 = lane & 15;

  __shared__ unsigned char W2s[128 * 256];   // 32KB fp8, [n][k'] swizzled

  // stage 32KB: 2048 16B chunks, 4/thread; colblk = v ^ (n&15)
#pragma unroll
  for (int it = 0; it < 4; ++it) {
    int e = it * 512 + tid;
    int n = e >> 4, v = e & 15;
    *(uint4*)&W2s[n * 256 + ((v ^ (n & 15)) << 4)] =
        *(const uint4*)(W2F8 + n * 256 + v * 16);
  }
  __syncthreads();

  const char* W2base = (const char*)&W2s[0];
  const int base_sw = l15 * 256 + ((((quad >> 1) ^ l15) & 15) << 4) + ((quad & 1) << 3);
  const int slot = blockIdx.x * 8 + wr;      // 0..4095
  const float b3v = b3[0];
  const float s16 = 0.0625f;                 // undo W2 x16 scale

  for (int s = 0; s < 3; ++s) {
    const int e2 = slot + s * 4096;
    if (e2 >= 9088) break;
    // decode e2 -> (b, jt, i)   [wave-uniform]
    const int b = (int)(((unsigned)e2 * 14769u) >> 24);   // e2 / 1136
    const int e = e2 - b * 1136;
    int jt = 0, base = 0;
    if (e >= 30)  { jt = 1; base = 30;  }
    if (e >= 92)  { jt = 2; base = 92;  }
    if (e >= 186) { jt = 3; base = 186; }
    if (e >= 312) { jt = 4; base = 312; }
    if (e >= 470) { jt = 5; base = 470; }
    if (e >= 660) { jt = 6; base = 660; }
    if (e >= 882) { jt = 7; base = 882; }
    const int i = e - base;                  // 0 .. jt*32+29

    const unsigned short* Pjb = PjH + ((b << 8) + jt * 32 + l15) * 256 + quad * 8;
    const unsigned short* PiRow = PiH + ((b << 8) + i) * 256 + quad * 8;

    floatx4 acc[2][8];
#pragma unroll
    for (int mt = 0; mt < 2; ++mt)
#pragma unroll
      for (int nt = 0; nt < 8; ++nt) acc[mt][nt] = (floatx4)0.f;

    union U4 { uint4 v; half8 h; };
    U4 piR[2], pjR[2][2];
    piR[0].v = *(const uint4*)(PiRow);
    pjR[0][0].v = *(const uint4*)(Pjb);
    pjR[0][1].v = *(const uint4*)(Pjb + 4096);   // mt=1: +16 rows

#pragma unroll
    for (int ks = 0; ks < 8; ++ks) {
      const int cur = ks & 1, nxt = cur ^ 1;
      if (ks < 7) {                    // depth-1 global prefetch
        piR[nxt].v = *(const uint4*)(PiRow + (ks + 1) * 32);
        pjR[nxt][0].v = *(const uint4*)(Pjb + (ks + 1) * 32);
        pjR[nxt][1].v = *(const uint4*)(Pjb + 4096 + (ks + 1) * 32);
      }
      // build A-frags: packed fp16 relu(Pi+Pj), then pack to e4m3
      const half8 s0 = __builtin_elementwise_max(piR[cur].h + pjR[cur][0].h,
                                                 (half8)(_Float16)0);
      const half8 s1 = __builtin_elementwise_max(piR[cur].h + pjR[cur][1].h,
                                                 (half8)(_Float16)0);
      const long a0 = pack_fp8(s0);
      const long a1 = pack_fp8(s1);
      const char* baddr = W2base + (base_sw ^ (ks << 5));
#pragma unroll
      for (int nt = 0; nt < 8; ++nt) {
        long bfr = *(const long*)(baddr + nt * 4096);
        acc[0][nt] = __builtin_amdgcn_mfma_f32_16x16x32_fp8_fp8(a0, bfr, acc[0][nt], 0, 0, 0);
        acc[1][nt] = __builtin_amdgcn_mfma_f32_16x16x32_fp8_fp8(a1, bfr, acc[1][nt], 0, 0, 0);
      }
    }

    // epilogue: score[j] = tanh(sum_n W3[n]*relu(C[j,n]/16 + b2[n]) + b3)
    float* orow = outm + ((b << 8) + i) * 256 + jt * 32;
#pragma unroll
    for (int mt = 0; mt < 2; ++mt) {
      float p0 = 0, p1 = 0, p2 = 0, p3 = 0;
#pragma unroll
      for (int nt = 0; nt < 8; ++nt) {
        float w3v = W3[nt * 16 + l15];
        float b2v = b2[nt * 16 + l15];
        floatx4 a = acc[mt][nt];
        p0 += fmaxf(fmaf(a[0], s16, b2v), 0.f) * w3v;
        p1 += fmaxf(fmaf(a[1], s16, b2v), 0.f) * w3v;
        p2 += fmaxf(fmaf(a[2], s16, b2v), 0.f) * w3v;
        p3 += fmaxf(fmaf(a[3], s16, b2v), 0.f) * w3v;
      }
#pragma unroll
      for (int m = 8; m >= 1; m >>= 1) {   // reduce over the 16 n-cols per quad
        p0 += __shfl_xor(p0, m, 16);
        p1 += __shfl_xor(p1, m, 16);
        p2 += __shfl_xor(p2, m, 16);
        p3 += __shfl_xor(p3, m, 16);
      }
      if (l15 == 0) {
        const int jl = jt * 32 + mt * 16 + quad * 4;   // global j of reg 0
        float ps[4] = {p0, p1, p2, p3};
#pragma unroll
        for (int r = 0; r < 4; ++r) {
          int j = jl + r;
          float sc = fast_tanh(ps[r] + b3v);
          bool valid = (j >= i + 2) && (j - i != 255);
          orow[mt * 16 + quad * 4 + r] = valid ? sc : 0.f;
        }
      }
    }
  }
}

extern "C" void kernel_launch(void* const* d_in, const int* in_sizes, int n_in,
                              void* d_out, int out_size, void* d_ws, size_t ws_size,
                              hipStream_t stream) {
  const float* x  = (const float*)d_in[0];   // [8,256,128]
  const float* W1 = (const float*)d_in[1];   // [512,256]
  const float* b1 = (const float*)d_in[2];   // [256]
  const float* W2 = (const float*)d_in[3];   // [256,128]
  const float* b2 = (const float*)d_in[4];   // [128]
  const float* W3 = (const float*)d_in[5];   // [128]
  const float* b3 = (const float*)d_in[6];   // [1]
  float* out = (float*)d_out;

  // ws (ushort units): PiH 524288 | PjH 524288 | W1T 131072 | xcat 524288 | W2F8 32KB
  unsigned short* PiH  = (unsigned short*)d_ws;
  unsigned short* PjH  = PiH + 524288;
  unsigned short* W1T  = PjH + 524288;
  unsigned short* xcat = W1T + 131072;
  unsigned char*  W2F8 = (unsigned char*)(xcat + 524288);

  k_prep<<<4680, 256, 0, stream>>>(x, W1, W2, out, W2F8, W1T, xcat);
  k_proj<<<256, 256, 0, stream>>>(xcat, W1T, b1, PiH, PjH);
  k_main<<<512, 512, 0, stream>>>(PiH, PjH, W2F8, b2, W3, b3, out + 2048);
}

// Round 13
// 103.888 us; speedup vs baseline: 1.0220x; 1.0220x over previous
//
#include <hip/hip_runtime.h>

// B=8, N=256, D=128, 2D=256.
// out = tour [8,256] (arange) ++ improvement_matrix [8,256,256].

typedef __attribute__((ext_vector_type(8))) short short8;
typedef __attribute__((ext_vector_type(8))) _Float16 half8;
typedef __attribute__((ext_vector_type(4))) float floatx4;

static __device__ __forceinline__ unsigned short f2bf(float f) {
  unsigned int x = __float_as_uint(f);
  x += 0x7fff + ((x >> 16) & 1);   // RNE fp32 -> bf16
  return (unsigned short)(x >> 16);
}

static __device__ __forceinline__ unsigned short f2h(float f) {
  _Float16 h = (_Float16)f;        // RNE fp32 -> fp16
  return __builtin_bit_cast(unsigned short, h);
}

static __device__ __forceinline__ float fast_tanh(float x) {
  float e = __expf(2.0f * fabsf(x));                       // e^{2|x|}
  float t = 1.0f - 2.0f * __builtin_amdgcn_rcpf(e + 1.0f); // in [0,1)
  return copysignf(t, x);
}

// pack 8 fp16 -> 8 OCP e4m3 bytes (via f32, v_cvt_pk_fp8_f32)
static __device__ __forceinline__ long pack_fp8(half8 s) {
  int lo = __builtin_amdgcn_cvt_pk_fp8_f32((float)s[0], (float)s[1], 0, false);
  lo = __builtin_amdgcn_cvt_pk_fp8_f32((float)s[2], (float)s[3], lo, true);
  int hi = __builtin_amdgcn_cvt_pk_fp8_f32((float)s[4], (float)s[5], 0, false);
  hi = __builtin_amdgcn_cvt_pk_fp8_f32((float)s[6], (float)s[7], hi, true);
  return (long)(unsigned)lo | ((long)hi << 32);
}

// ---- k_prep: tour | zero matrix | W2->fp8(x16) T | W1->bf16 T | xcat bf16 --
__global__ __launch_bounds__(256) void k_prep(
    const float* __restrict__ x, const float* __restrict__ W1,
    const float* __restrict__ W2, float* __restrict__ out,
    unsigned char* __restrict__ W2F8, unsigned short* __restrict__ W1T,
    unsigned short* __restrict__ xcat) {
  int e = blockIdx.x * 256 + threadIdx.x;   // grid covers 1198080
  if (e < 2048) {
    out[e] = (float)(e & 255);              // improved_tour rows = arange
  } else if (e < 526336) {
    out[e] = 0.f;                           // zero matrix (uncovered tiles)
  } else if (e < 542720) {
    int t = e - 526336;                     // 16384 k-pairs of W2
    int p = t >> 7, n = t & 127;            // p = k/2, n = out channel
    float f0 = W2[(2 * p) * 128 + n] * 16.f;       // x16: into e4m3 normal range
    float f1 = W2[(2 * p + 1) * 128 + n] * 16.f;
    int v = __builtin_amdgcn_cvt_pk_fp8_f32(f0, f1, 0, false);
    *(unsigned short*)(W2F8 + n * 256 + 2 * p) = (unsigned short)(v & 0xffff);
  } else if (e < 673792) {
    int e3 = e - 542720;                    // 131072: W1T [512 n][256 k]
    int n = e3 >> 8, k = e3 & 255;
    W1T[e3] = f2bf(W1[((k + (n & 256)) << 8) + (n & 255)]);
  } else {
    int e4 = e - 673792;                    // 524288: xcat [2048 r][256 k]
    int r = e4 >> 8, k = e4 & 255;
    int pos = r & 255;
    int pos2 = (k < 128) ? pos : ((pos + 1) & 255);
    xcat[e4] = f2bf(x[(((r >> 8) << 8) + pos2) * 128 + (k & 127)]);
  }
}

// ---- k_proj: MFMA GEMM  [2048 rows x 256 K] @ [K x 512 ch] -> PiH | PjH ----
__global__ __launch_bounds__(256) void k_proj(
    const unsigned short* __restrict__ xcat, const unsigned short* __restrict__ W1T,
    const float* __restrict__ b1, unsigned short* __restrict__ PiH,
    unsigned short* __restrict__ PjH) {
  const int mg = blockIdx.x >> 3;       // 0..31 row-tile
  const int ng = blockIdx.x & 7;        // 0..7 channel-tile
  const int tid = threadIdx.x;
  const int wr = tid >> 6, lane = tid & 63, quad = lane >> 4, l15 = lane & 15;

  __shared__ unsigned short As[64 * 256];   // 32KB rows tile (swizzled)
  __shared__ unsigned short Bs[64 * 256];   // 32KB W1T tile (swizzled)

#pragma unroll
  for (int it = 0; it < 8; ++it) {
    int e = it * 256 + tid;
    int r = e >> 5, v = e & 31;
    int col = ((v & 16) | ((v ^ (r & 15)) & 15)) << 3;
    *(uint4*)&As[r * 256 + col] = *(const uint4*)(xcat + (mg * 64 + r) * 256 + v * 8);
    *(uint4*)&Bs[r * 256 + col] = *(const uint4*)(W1T + (ng * 64 + r) * 256 + v * 8);
  }
  __syncthreads();

  floatx4 acc[4];
#pragma unroll
  for (int mt = 0; mt < 4; ++mt) acc[mt] = (floatx4)0.f;

  const char* Ab = (const char*)As;
  const char* Bb = (const char*)Bs + wr * 16 * 512;
  const int base_sw = l15 * 512 + ((quad ^ l15) << 4);

#pragma unroll
  for (int ks = 0; ks < 8; ++ks) {
    const int swz = base_sw ^ (ks << 6);
    short8 bfr = *(const short8*)(Bb + swz);
#pragma unroll
    for (int mt = 0; mt < 4; ++mt) {
      short8 afr = *(const short8*)(Ab + mt * 8192 + swz);
      acc[mt] = __builtin_amdgcn_mfma_f32_16x16x32_bf16(afr, bfr, acc[mt], 0, 0, 0);
    }
  }

  const int ch = ng * 64 + wr * 16 + l15;          // 0..511 (wave-uniform side)
  const float bias = (ch < 256) ? b1[ch] : 0.f;
  unsigned short* dst = (ch < 256) ? PiH : PjH;
  const int chan = ch & 255;
#pragma unroll
  for (int mt = 0; mt < 4; ++mt)
#pragma unroll
    for (int r = 0; r < 4; ++r) {
      int row = mg * 64 + mt * 16 + quad * 4 + r;  // global row b*256+pos
      dst[row * 256 + chan] = f2h(acc[mt][r] + bias);
    }
}

// ---- k_main: packed items + fp8 pair-GEMM + BATCHED B-frag ds_reads. ------
// 9088 items (1136/b x 8b); grid 2272 x 256thr (4 waves, 1 item each).
// Key fix vs R9-R12: all 8 ds_read_b64 of a ks-iteration issue back-to-back
// into bfr[8] (16 regs at fp8) BEFORE the MFMA burst -> ONE lgkm wait per
// iteration instead of 8 serial read->wait->MFMA stalls. __launch_bounds__
// (256,3): 170-reg cap fits ~80 arch + 64 acc, 3 blocks/CU (96KB LDS) =
// 12 waves/CU.
__global__ __launch_bounds__(256, 3) void k_main(
    const unsigned short* __restrict__ PiH, const unsigned short* __restrict__ PjH,
    const unsigned char* __restrict__ W2F8, const float* __restrict__ b2,
    const float* __restrict__ W3, const float* __restrict__ b3,
    float* __restrict__ outm) {
  const int tid = threadIdx.x;
  const int wr = tid >> 6;              // wave 0..3
  const int lane = tid & 63, quad = lane >> 4, l15 = lane & 15;

  __shared__ unsigned char W2s[128 * 256];   // 32KB fp8, [n][k'] swizzled

  // stage 32KB: 2048 16B chunks, 8/thread; colblk = v ^ (n&15)
#pragma unroll
  for (int it = 0; it < 8; ++it) {
    int e = it * 256 + tid;
    int n = e >> 4, v = e & 15;
    *(uint4*)&W2s[n * 256 + ((v ^ (n & 15)) << 4)] =
        *(const uint4*)(W2F8 + n * 256 + v * 16);
  }
  __syncthreads();

  // decode packed item e2 -> (b, jt, i)   [wave-uniform]
  const int e2 = blockIdx.x * 4 + wr;        // 0..9087
  const int b = (int)(((unsigned)e2 * 14769u) >> 24);   // e2 / 1136
  const int e = e2 - b * 1136;
  int jt = 0, base = 0;
  if (e >= 30)  { jt = 1; base = 30;  }
  if (e >= 92)  { jt = 2; base = 92;  }
  if (e >= 186) { jt = 3; base = 186; }
  if (e >= 312) { jt = 4; base = 312; }
  if (e >= 470) { jt = 5; base = 470; }
  if (e >= 660) { jt = 6; base = 660; }
  if (e >= 882) { jt = 7; base = 882; }
  const int i = e - base;                    // 0 .. jt*32+29

  const char* W2base = (const char*)&W2s[0];
  const int base_sw = l15 * 256 + ((((quad >> 1) ^ l15) & 15) << 4) + ((quad & 1) << 3);
  const unsigned short* Pjb = PjH + ((b << 8) + jt * 32 + l15) * 256 + quad * 8;
  const unsigned short* PiRow = PiH + ((b << 8) + i) * 256 + quad * 8;

  floatx4 acc[2][8];
#pragma unroll
  for (int mt = 0; mt < 2; ++mt)
#pragma unroll
    for (int nt = 0; nt < 8; ++nt) acc[mt][nt] = (floatx4)0.f;

  union U4 { uint4 v; half8 h; };
  U4 piR[2], pjR[2][2];
  piR[0].v = *(const uint4*)(PiRow);
  pjR[0][0].v = *(const uint4*)(Pjb);
  pjR[0][1].v = *(const uint4*)(Pjb + 4096);   // mt=1: +16 rows

#pragma unroll
  for (int ks = 0; ks < 8; ++ks) {
    const int cur = ks & 1, nxt = cur ^ 1;
    // (1) batch this iteration's 8 B-frag LDS reads -> one lgkm wait
    long bfr[8];
    const char* baddr = W2base + (base_sw ^ (ks << 5));
#pragma unroll
    for (int nt = 0; nt < 8; ++nt) bfr[nt] = *(const long*)(baddr + nt * 4096);
    // (2) depth-1 global prefetch for ks+1
    if (ks < 7) {
      piR[nxt].v = *(const uint4*)(PiRow + (ks + 1) * 32);
      pjR[nxt][0].v = *(const uint4*)(Pjb + (ks + 1) * 32);
      pjR[nxt][1].v = *(const uint4*)(Pjb + 4096 + (ks + 1) * 32);
    }
    // (3) build A-frags: packed fp16 relu(Pi+Pj), then pack to e4m3
    const half8 s0 = __builtin_elementwise_max(piR[cur].h + pjR[cur][0].h,
                                               (half8)(_Float16)0);
    const half8 s1 = __builtin_elementwise_max(piR[cur].h + pjR[cur][1].h,
                                               (half8)(_Float16)0);
    const long a0 = pack_fp8(s0);
    const long a1 = pack_fp8(s1);
    // (4) MFMA burst
#pragma unroll
    for (int nt = 0; nt < 8; ++nt) {
      acc[0][nt] = __builtin_amdgcn_mfma_f32_16x16x32_fp8_fp8(a0, bfr[nt], acc[0][nt], 0, 0, 0);
      acc[1][nt] = __builtin_amdgcn_mfma_f32_16x16x32_fp8_fp8(a1, bfr[nt], acc[1][nt], 0, 0, 0);
    }
  }

  // epilogue: score[j] = tanh(sum_n W3[n]*relu(C[j,n]/16 + b2[n]) + b3)
  float* orow = outm + ((b << 8) + i) * 256 + jt * 32;
  const float b3v = b3[0];
  const float s16 = 0.0625f;               // undo W2 x16 scale
#pragma unroll
  for (int mt = 0; mt < 2; ++mt) {
    float p0 = 0, p1 = 0, p2 = 0, p3 = 0;
#pragma unroll
    for (int nt = 0; nt < 8; ++nt) {
      float w3v = W3[nt * 16 + l15];
      float b2v = b2[nt * 16 + l15];
      floatx4 a = acc[mt][nt];
      p0 += fmaxf(fmaf(a[0], s16, b2v), 0.f) * w3v;
      p1 += fmaxf(fmaf(a[1], s16, b2v), 0.f) * w3v;
      p2 += fmaxf(fmaf(a[2], s16, b2v), 0.f) * w3v;
      p3 += fmaxf(fmaf(a[3], s16, b2v), 0.f) * w3v;
    }
#pragma unroll
    for (int m = 8; m >= 1; m >>= 1) {   // reduce over the 16 n-cols per quad
      p0 += __shfl_xor(p0, m, 16);
      p1 += __shfl_xor(p1, m, 16);
      p2 += __shfl_xor(p2, m, 16);
      p3 += __shfl_xor(p3, m, 16);
    }
    if (l15 == 0) {
      const int jl = jt * 32 + mt * 16 + quad * 4;   // global j of reg 0
      float ps[4] = {p0, p1, p2, p3};
#pragma unroll
      for (int r = 0; r < 4; ++r) {
        int j = jl + r;
        float sc = fast_tanh(ps[r] + b3v);
        bool valid = (j >= i + 2) && (j - i != 255);
        orow[mt * 16 + quad * 4 + r] = valid ? sc : 0.f;
      }
    }
  }
}

extern "C" void kernel_launch(void* const* d_in, const int* in_sizes, int n_in,
                              void* d_out, int out_size, void* d_ws, size_t ws_size,
                              hipStream_t stream) {
  const float* x  = (const float*)d_in[0];   // [8,256,128]
  const float* W1 = (const float*)d_in[1];   // [512,256]
  const float* b1 = (const float*)d_in[2];   // [256]
  const float* W2 = (const float*)d_in[3];   // [256,128]
  const float* b2 = (const float*)d_in[4];   // [128]
  const float* W3 = (const float*)d_in[5];   // [128]
  const float* b3 = (const float*)d_in[6];   // [1]
  float* out = (float*)d_out;

  // ws (ushort units): PiH 524288 | PjH 524288 | W1T 131072 | xcat 524288 | W2F8 32KB
  unsigned short* PiH  = (unsigned short*)d_ws;
  unsigned short* PjH  = PiH + 524288;
  unsigned short* W1T  = PjH + 524288;
  unsigned short* xcat = W1T + 131072;
  unsigned char*  W2F8 = (unsigned char*)(xcat + 524288);

  k_prep<<<4680, 256, 0, stream>>>(x, W1, W2, out, W2F8, W1T, xcat);
  k_proj<<<256, 256, 0, stream>>>(xcat, W1T, b1, PiH, PjH);
  k_main<<<2272, 256, 0, stream>>>(PiH, PjH, W2F8, b2, W3, b3, out + 2048);
}